// Round 9
// baseline (561.002 us; speedup 1.0000x reference)
//
#include <hip/hip_runtime.h>

#define DI __device__ __forceinline__

typedef unsigned short u16;
typedef short short8 __attribute__((ext_vector_type(8)));
typedef float f32x4 __attribute__((ext_vector_type(4)));
typedef u16 u16x4 __attribute__((ext_vector_type(4)));

#define NN 2048
#define CC 128
#define BB 32
#define DD 128
#define OO 128
#define KI 384
#define JJ 49152  // 128*384

DI u16 f2bf(float f) {
  union { float f; unsigned u; } v; v.f = f;
  return (u16)((v.u + 0x7fffu + ((v.u >> 16) & 1u)) >> 16);  // RNE
}
DI float bf2f(u16 h) {
  union { unsigned u; float f; } v; v.u = ((unsigned)h) << 16;
  return v.f;
}

typedef __attribute__((address_space(3))) unsigned int lds_u32;
typedef __attribute__((address_space(1))) unsigned int glob_u32;

DI void gl16(const void* g, void* l) {
  __builtin_amdgcn_global_load_lds((const glob_u32*)g, (lds_u32*)l, 16, 0, 0);
}

// ---------------- LayerNorm: e = LN(emb)*gamma + beta; emit fp32 + bf16 hi/lo ----------------
__global__ __launch_bounds__(128)
void k_ln(const float* __restrict__ emb, const float* __restrict__ gam,
          const float* __restrict__ bet, float* __restrict__ e,
          u16* __restrict__ ehi, u16* __restrict__ elo) {
  __shared__ float s2[2], q2[2];
  const int n = blockIdx.x, t = threadIdx.x;
  const float v = emb[(size_t)n * DD + t];
  float s = v;
  #pragma unroll
  for (int off = 32; off; off >>= 1) s += __shfl_down(s, off);
  if ((t & 63) == 0) s2[t >> 6] = s;
  __syncthreads();
  const float mu = (s2[0] + s2[1]) * (1.f / 128.f);
  const float dv = v - mu;
  float q = dv * dv;
  #pragma unroll
  for (int off = 32; off; off >>= 1) q += __shfl_down(q, off);
  if ((t & 63) == 0) q2[t >> 6] = q;
  __syncthreads();
  const float var = (q2[0] + q2[1]) * (1.f / 128.f);
  const float ev = dv * rsqrtf(var + 1e-12f) * gam[t] + bet[t];
  e[(size_t)n * DD + t] = ev;
  const u16 hi = f2bf(ev);
  ehi[(size_t)n * DD + t] = hi;
  elo[(size_t)n * DD + t] = f2bf(ev - bf2f(hi));
}

// ---------------- Z = elu(e e^T) via split-bf16 MFMA (hi*hi + hi*lo + lo*hi) ----------------
__global__ __launch_bounds__(256, 2)
void k_zg(const u16* __restrict__ ehi, const u16* __restrict__ elo, float* __restrict__ Z) {
  __shared__ char smem[32768];
  const int t = threadIdx.x;
  const int w = t >> 6, l = t & 63;
  const int l15 = l & 15, kg = l >> 4;
  const int wr = (w >> 1) * 64, wc = (w & 1) * 64;
  const int row0 = blockIdx.x * 128, col0 = blockIdx.y * 128;

  f32x4 acc[4][4];
  #pragma unroll
  for (int i = 0; i < 4; ++i)
    #pragma unroll
    for (int j = 0; j < 4; ++j) { f32x4 z = {0.f, 0.f, 0.f, 0.f}; acc[i][j] = z; }

  const int ra = t >> 3, sa = t & 7;
  #pragma unroll 1
  for (int it = 0; it < 6; ++it) {
    const int term = it >> 1;
    const int k0 = (it & 1) * 64;
    const u16* As = (term == 2) ? elo : ehi;
    const u16* Bs = (term == 1) ? elo : ehi;
    __syncthreads();
    #pragma unroll
    for (int i = 0; i < 4; ++i) {
      const int r = i * 32 + ra;
      const int ss = sa ^ (r & 7);
      gl16(As + (size_t)(row0 + r) * DD + k0 + ss * 8, smem + i * 4096 + t * 16);
      gl16(Bs + (size_t)(col0 + r) * DD + k0 + ss * 8, smem + 16384 + i * 4096 + t * 16);
    }
    __syncthreads();
    short8 af[2][4], bfv[2][4];
    #pragma unroll
    for (int mt = 0; mt < 4; ++mt) {
      const int row = wr + mt * 16 + l15;
      #pragma unroll
      for (int ks = 0; ks < 2; ++ks) {
        const int sl = (ks * 4 + kg) ^ (row & 7);
        af[ks][mt] = *(const short8*)(smem + row * 128 + sl * 16);
      }
    }
    #pragma unroll
    for (int nt = 0; nt < 4; ++nt) {
      const int row = wc + nt * 16 + l15;
      #pragma unroll
      for (int ks = 0; ks < 2; ++ks) {
        const int sl = (ks * 4 + kg) ^ (row & 7);
        bfv[ks][nt] = *(const short8*)(smem + 16384 + row * 128 + sl * 16);
      }
    }
    #pragma unroll
    for (int ks = 0; ks < 2; ++ks)
      #pragma unroll
      for (int mt = 0; mt < 4; ++mt)
        #pragma unroll
        for (int nt = 0; nt < 4; ++nt)
          acc[mt][nt] = __builtin_amdgcn_mfma_f32_16x16x32_bf16(af[ks][mt], bfv[ks][nt], acc[mt][nt], 0, 0, 0);
  }
  #pragma unroll
  for (int mt = 0; mt < 4; ++mt) {
    const int n_ = row0 + wr + mt * 16 + kg * 4;
    #pragma unroll
    for (int nt = 0; nt < 4; ++nt) {
      const int m_ = col0 + wc + nt * 16 + l15;
      #pragma unroll
      for (int r = 0; r < 4; ++r) {
        const float v = acc[mt][nt][r];
        __builtin_nontemporal_store((v > 0.f) ? v : expm1f(v),
                                    Z + (size_t)(n_ + r) * NN + m_);
      }
    }
  }
}

// ---------------- row softmax over Z -> A_bf16 ----------------
__global__ __launch_bounds__(256)
void k_sm(const float* __restrict__ Z, u16* __restrict__ Abf) {
  __shared__ float red[4];
  const int n = blockIdx.x, t = threadIdx.x, w = t >> 6;
  const float* zr = Z + (size_t)n * NN + t * 8;
  float4 v0 = *(const float4*)(zr);
  float4 v1 = *(const float4*)(zr + 4);
  float z[8] = {v0.x, v0.y, v0.z, v0.w, v1.x, v1.y, v1.z, v1.w};
  float mx = z[0];
  #pragma unroll
  for (int i = 1; i < 8; ++i) mx = fmaxf(mx, z[i]);
  #pragma unroll
  for (int off = 32; off; off >>= 1) mx = fmaxf(mx, __shfl_xor(mx, off));
  if ((t & 63) == 0) red[w] = mx;
  __syncthreads();
  mx = fmaxf(fmaxf(red[0], red[1]), fmaxf(red[2], red[3]));
  __syncthreads();
  float sm = 0.f;
  #pragma unroll
  for (int i = 0; i < 8; ++i) { z[i] = expf(z[i] - mx); sm += z[i]; }
  #pragma unroll
  for (int off = 32; off; off >>= 1) sm += __shfl_xor(sm, off);
  if ((t & 63) == 0) red[w] = sm;
  __syncthreads();
  const float inv = 1.f / (red[0] + red[1] + red[2] + red[3]);
  short8 pk;
  #pragma unroll
  for (int i = 0; i < 8; ++i) pk[i] = (short)f2bf(z[i] * inv);
  *(short8*)(Abf + (size_t)n * NN + t * 8) = pk;  // keep cached: g0/g1 re-read Abf
}

// ---------------- transpose-cast x[b][m][c] -> xt[b][c][m] + xbf[b][m][c] (bf16) ----------------
__global__ __launch_bounds__(256)
void k_tc(const float* __restrict__ x, u16* __restrict__ xt, u16* __restrict__ xbf) {
  __shared__ float ld[64 * 68];
  const int t = threadIdx.x;
  const int m0 = blockIdx.x * 64, c0 = blockIdx.y * 64, b = blockIdx.z;
  const float* xb = x + (size_t)b * NN * CC;
  u16* xfb = xbf + (size_t)b * NN * CC;
  #pragma unroll
  for (int i = 0; i < 4; ++i) {
    const int m = i * 16 + (t >> 4), c4 = (t & 15) * 4;
    const float4 v = *(const float4*)&xb[(size_t)(m0 + m) * CC + c0 + c4];
    *(float4*)&ld[m * 68 + c4] = v;
    u16x4 cv = { f2bf(v.x), f2bf(v.y), f2bf(v.z), f2bf(v.w) };
    __builtin_nontemporal_store(cv, (u16x4*)&xfb[(size_t)(m0 + m) * CC + c0 + c4]);
  }
  __syncthreads();
  u16* xtb = xt + (size_t)b * CC * NN;
  #pragma unroll
  for (int i = 0; i < 4; ++i) {
    const int c = i * 16 + (t >> 4), m4 = (t & 15) * 4;
    u16x4 v = { f2bf(ld[(m4 + 0) * 68 + c]), f2bf(ld[(m4 + 1) * 68 + c]),
                f2bf(ld[(m4 + 2) * 68 + c]), f2bf(ld[(m4 + 3) * 68 + c]) };
    __builtin_nontemporal_store(v, (u16x4*)&xtb[(size_t)(c0 + c) * NN + m0 + m4]);
  }
}

// ---------------- transpose-cast Wp[d][ki][o] -> Wp_t[(o*384+ki)][d] (bf16) ----------------
__global__ __launch_bounds__(256)
void k_wpt(const float* __restrict__ wp, u16* __restrict__ wpt) {
  __shared__ float ld[64 * 68];
  const int t = threadIdx.x;
  const int d0 = blockIdx.x * 64, o0 = blockIdx.y * 64, ki = blockIdx.z;
  #pragma unroll
  for (int i = 0; i < 4; ++i) {
    const int d = i * 16 + (t >> 4), o4 = (t & 15) * 4;
    *(float4*)&ld[d * 68 + o4] = *(const float4*)&wp[((size_t)(d0 + d) * KI + ki) * OO + o0 + o4];
  }
  __syncthreads();
  #pragma unroll
  for (int i = 0; i < 4; ++i) {
    const int o = i * 16 + (t >> 4), d4 = (t & 15) * 4;
    u16x4 v = { f2bf(ld[(d4 + 0) * 68 + o]), f2bf(ld[(d4 + 1) * 68 + o]),
                f2bf(ld[(d4 + 2) * 68 + o]), f2bf(ld[(d4 + 3) * 68 + o]) };
    __builtin_nontemporal_store(v, (u16x4*)&wpt[((size_t)(o0 + o) * KI + ki) * DD + d0 + d4]);
  }
}

// ---------------- bias[n][o] = e[n]·bias_pool[:,o] (fp32) ----------------
__global__ __launch_bounds__(128)
void k_bias(const float* __restrict__ e, const float* __restrict__ bp, float* __restrict__ bias) {
  const int n = blockIdx.x, o = threadIdx.x;
  const float* er = e + (size_t)n * DD;
  float acc = 0.f;
  for (int d = 0; d < 128; ++d) acc = fmaf(er[d], bp[(size_t)d * OO + o], acc);
  bias[(size_t)n * OO + o] = acc;
}

// ---------------- shared 128x128-tile bf16 MFMA GEMM (m97-style, BK=64) ----------------
// MODE 0: D[n][c] = sum_m A[n][m]*xt[b][c][m]; store y1t[b][c][n] + y1[b][n][c] (LDS bounce).
// MODE 1: D[c][n] = sum_m y1t[b][c][m]*A[n][m]; store y2[b][n][c] = 2*D - x (x as bf16).
// MODE 2: D[j][nl] = sum_d Wp_t[j][d]*ehi[n][d]; store to tile-major wt2[jt][node][128]:
//         each block writes one dense 32KB region; every wave completes full cache
//         lines (round-7 evidence: pattern class alone didn't fix the 2 TB/s write,
//         so combine dense layout + nontemporal to stop L2 pollution + partial lines).
// All big intermediate stores are nontemporal (write-once, read-much-later streams).
template<int MODE>
__global__ __launch_bounds__(256, 2)
void gemm_bf16(const u16* __restrict__ Ab, int lda,
               const u16* __restrict__ Bb, int ldb, int ksteps,
               u16* __restrict__ out0, u16* __restrict__ out1,
               const u16* __restrict__ xaux) {
  __shared__ char smem[34816];  // 32KB staging; 34.8KB bounce (MODE 0)
  const int t = threadIdx.x;
  const int w = t >> 6, l = t & 63;
  const int l15 = l & 15, kg = l >> 4;
  const int wr = (w >> 1) * 64, wc = (w & 1) * 64;

  const u16 *Abase, *Bbase;
  int row0 = 0, col0 = 0, b = 0;
  if constexpr (MODE == 0 || MODE == 1) {
    // grid is dim3(16,32) = 512 blocks; hw-linear id round-robins XCDs (%8)
    const int lin = blockIdx.x + (int)gridDim.x * blockIdx.y;
    const int xcd = lin & 7, pos = lin >> 3;
    const int tile = xcd * 2 + (pos & 1);  // 0..15 n-tile
    b = pos >> 1;                           // 0..31 batch
    if constexpr (MODE == 0) {
      row0 = tile * 128;
      Abase = Ab + (size_t)row0 * lda;
      Bbase = Bb + (size_t)b * CC * NN;
    } else {
      col0 = tile * 128;
      Abase = Ab + (size_t)b * CC * NN;
      Bbase = Bb + (size_t)col0 * NN;
    }
  } else {
    row0 = blockIdx.x * 128; col0 = blockIdx.y * 128;
    Abase = Ab + (size_t)row0 * 128;
    Bbase = Bb + (size_t)col0 * 128;
  }

  f32x4 acc[4][4];
  #pragma unroll
  for (int i = 0; i < 4; ++i)
    #pragma unroll
    for (int j = 0; j < 4; ++j) { f32x4 z = {0.f, 0.f, 0.f, 0.f}; acc[i][j] = z; }

  const int ra = t >> 3, sa = t & 7;
  for (int kt = 0; kt < ksteps; ++kt) {
    const int k0 = kt * 64;
    __syncthreads();
    #pragma unroll
    for (int i = 0; i < 4; ++i) {
      const int r = i * 32 + ra;
      const int ss = sa ^ (r & 7);
      gl16(Abase + (size_t)r * lda + k0 + ss * 8, smem + i * 4096 + t * 16);
    }
    #pragma unroll
    for (int i = 0; i < 4; ++i) {
      const int r = i * 32 + ra;
      const int ss = sa ^ (r & 7);
      gl16(Bbase + (size_t)r * ldb + k0 + ss * 8, smem + 16384 + i * 4096 + t * 16);
    }
    __syncthreads();
    short8 af[2][4], bfv[2][4];
    #pragma unroll
    for (int mt = 0; mt < 4; ++mt) {
      const int row = wr + mt * 16 + l15;
      #pragma unroll
      for (int ks = 0; ks < 2; ++ks) {
        const int sl = (ks * 4 + kg) ^ (row & 7);
        af[ks][mt] = *(const short8*)(smem + row * 128 + sl * 16);
      }
    }
    #pragma unroll
    for (int nt = 0; nt < 4; ++nt) {
      const int row = wc + nt * 16 + l15;
      #pragma unroll
      for (int ks = 0; ks < 2; ++ks) {
        const int sl = (ks * 4 + kg) ^ (row & 7);
        bfv[ks][nt] = *(const short8*)(smem + 16384 + row * 128 + sl * 16);
      }
    }
    #pragma unroll
    for (int ks = 0; ks < 2; ++ks)
      #pragma unroll
      for (int mt = 0; mt < 4; ++mt)
        #pragma unroll
        for (int nt = 0; nt < 4; ++nt)
          acc[mt][nt] = __builtin_amdgcn_mfma_f32_16x16x32_bf16(af[ks][mt], bfv[ks][nt], acc[mt][nt], 0, 0, 0);
  }

  if constexpr (MODE == 0) {
    u16* y1t = out0 + (size_t)b * CC * NN;
    #pragma unroll
    for (int mt = 0; mt < 4; ++mt) {
      const int n_ = row0 + wr + mt * 16 + kg * 4;
      #pragma unroll
      for (int nt = 0; nt < 4; ++nt) {
        const int c_ = wc + nt * 16 + l15;
        u16x4 v = { f2bf(acc[mt][nt][0]), f2bf(acc[mt][nt][1]),
                    f2bf(acc[mt][nt][2]), f2bf(acc[mt][nt][3]) };
        __builtin_nontemporal_store(v, (u16x4*)(y1t + (size_t)c_ * NN + n_));
      }
    }
    __syncthreads();
    u16* L = (u16*)smem;  // [128 n][136 c]
    #pragma unroll
    for (int mt = 0; mt < 4; ++mt) {
      const int nl = wr + mt * 16 + kg * 4;
      #pragma unroll
      for (int nt = 0; nt < 4; ++nt) {
        const int c_ = wc + nt * 16 + l15;
        #pragma unroll
        for (int r = 0; r < 4; ++r) L[(nl + r) * 136 + c_] = f2bf(acc[mt][nt][r]);
      }
    }
    __syncthreads();
    u16* y1o = out1 + (size_t)b * NN * CC;
    const int nl2 = t >> 1, ch = (t & 1) * 64;
    #pragma unroll
    for (int q = 0; q < 8; ++q) {
      short8 vv = *(const short8*)(L + nl2 * 136 + ch + q * 8);
      __builtin_nontemporal_store(vv, (short8*)(y1o + (size_t)(row0 + nl2) * CC + ch + q * 8));
    }
  } else if constexpr (MODE == 1) {
    const u16* xb = xaux + (size_t)b * NN * CC;
    u16* y2b = out0 + (size_t)b * NN * CC;
    #pragma unroll
    for (int mt = 0; mt < 4; ++mt) {
      const int c_ = wr + mt * 16 + kg * 4;
      #pragma unroll
      for (int nt = 0; nt < 4; ++nt) {
        const int n_ = col0 + wc + nt * 16 + l15;
        const u16x4 xv = *(const u16x4*)(xb + (size_t)n_ * CC + c_);
        u16x4 v = { f2bf(2.f * acc[mt][nt][0] - bf2f(xv[0])),
                    f2bf(2.f * acc[mt][nt][1] - bf2f(xv[1])),
                    f2bf(2.f * acc[mt][nt][2] - bf2f(xv[2])),
                    f2bf(2.f * acc[mt][nt][3] - bf2f(xv[3])) };
        __builtin_nontemporal_store(v, (u16x4*)(y2b + (size_t)n_ * CC + c_));
      }
    }
  } else {
    // tile-major W: plane jt = row0/128, within-plane [node][128 jsub], dense 32KB/block
    u16* wtb = out0 + (size_t)(row0 >> 7) * ((size_t)gridDim.y << 14);
    #pragma unroll
    for (int mt = 0; mt < 4; ++mt) {
      const int jl = wr + mt * 16 + kg * 4;
      #pragma unroll
      for (int nt = 0; nt < 4; ++nt) {
        const int nl = col0 + wc + nt * 16 + l15;
        u16x4 v = { f2bf(acc[mt][nt][0]), f2bf(acc[mt][nt][1]),
                    f2bf(acc[mt][nt][2]), f2bf(acc[mt][nt][3]) };
        __builtin_nontemporal_store(v, (u16x4*)(wtb + (size_t)nl * 128 + jl));
      }
    }
  }
}

// ---------------- per-node GEMM: out[b][n][o] = X~[32,384]@W~[384,128] + bias ----------------
// W read from tile-major wt2[jt][node][128]: element (o,ki) -> plane 3*o + ki/128,
// jsub = ki%128 (KI = 384 = 3*128, ki%128 == ch2-local offset, verified).
__global__ __launch_bounds__(256, 4)
void stage_b(const u16* __restrict__ xbf, const u16* __restrict__ y1,
             const u16* __restrict__ y2, const u16* __restrict__ Wt,
             const float* __restrict__ bias, float* __restrict__ out, int nbase) {
  const int t = threadIdx.x, w = t >> 6, l = t & 63;
  const int l15 = l & 15, kg = l >> 4;
  const int n = nbase + blockIdx.x;
  const size_t pstride = (size_t)gridDim.x << 7;  // chunk*128 elements per plane
  const u16* Wn = Wt + (size_t)blockIdx.x * 128;  // node's 256B row within each plane
  f32x4 acc[2][2];
  {
    f32x4 z = {0.f, 0.f, 0.f, 0.f};
    acc[0][0] = z; acc[0][1] = z; acc[1][0] = z; acc[1][1] = z;
  }
  #pragma unroll
  for (int ch2 = 0; ch2 < 3; ++ch2) {
    const u16* src = (ch2 == 0) ? xbf : (ch2 == 1) ? y1 : y2;
    #pragma unroll
    for (int ks = 0; ks < 4; ++ks) {
      short8 af[2];
      #pragma unroll
      for (int mt = 0; mt < 2; ++mt) {
        const int bb2 = mt * 16 + l15;
        af[mt] = *(const short8*)(src + ((size_t)bb2 * NN + n) * CC + ks * 32 + kg * 8);
      }
      #pragma unroll
      for (int ot = 0; ot < 2; ++ot) {
        const int o = w * 32 + ot * 16 + l15;
        short8 bv = *(const short8*)(Wn + (size_t)(3 * o + ch2) * pstride + ks * 32 + kg * 8);
        acc[0][ot] = __builtin_amdgcn_mfma_f32_16x16x32_bf16(af[0], bv, acc[0][ot], 0, 0, 0);
        acc[1][ot] = __builtin_amdgcn_mfma_f32_16x16x32_bf16(af[1], bv, acc[1][ot], 0, 0, 0);
      }
    }
  }
  #pragma unroll
  for (int ot = 0; ot < 2; ++ot) {
    const int o = w * 32 + ot * 16 + l15;
    const float bs = bias[(size_t)n * OO + o];
    #pragma unroll
    for (int mt = 0; mt < 2; ++mt)
      #pragma unroll
      for (int r = 0; r < 4; ++r) {
        const int bb2 = mt * 16 + kg * 4 + r;
        __builtin_nontemporal_store(acc[mt][ot][r] + bs,
                                    out + ((size_t)bb2 * NN + n) * OO + o);
      }
  }
}

extern "C" void kernel_launch(void* const* d_in, const int* in_sizes, int n_in,
                              void* d_out, int out_size, void* d_ws, size_t ws_size,
                              hipStream_t stream) {
  (void)in_sizes; (void)n_in; (void)out_size;
  const float* x   = (const float*)d_in[0];
  const float* emb = (const float*)d_in[1];
  const float* wp  = (const float*)d_in[2];
  const float* bp  = (const float*)d_in[3];
  const float* gam = (const float*)d_in[4];
  const float* bet = (const float*)d_in[5];
  float* out = (float*)d_out;
  char* ws = (char*)d_ws;

  size_t off = 0;
  auto alloc = [&](size_t bytes) -> void* {
    void* p = (void*)(ws + off);
    off += (bytes + 511) & ~(size_t)511;
    return p;
  };
  float* e    = (float*)alloc((size_t)NN * DD * 4);
  u16*   ehi  = (u16*)  alloc((size_t)NN * DD * 2);
  u16*   elo  = (u16*)  alloc((size_t)NN * DD * 2);
  float* bias = (float*)alloc((size_t)NN * OO * 4);
  u16*   Abf  = (u16*)  alloc((size_t)NN * NN * 2);
  u16*   xt   = (u16*)  alloc((size_t)BB * CC * NN * 2);
  u16*   xbf  = (u16*)  alloc((size_t)BB * NN * CC * 2);
  u16*   y1t  = (u16*)  alloc((size_t)BB * CC * NN * 2);
  u16*   y1   = (u16*)  alloc((size_t)BB * NN * CC * 2);
  u16*   y2   = (u16*)  alloc((size_t)BB * NN * CC * 2);
  u16*   wpt  = (u16*)  alloc((size_t)JJ * DD * 2);
  const size_t rem = (ws_size > off) ? (ws_size - off) : 0;
  int chunk = 1024;  // 96MB W-chunk
  while (chunk > 128 && (size_t)chunk * JJ * 2 > rem) chunk >>= 1;
  size_t wt_bytes = (size_t)chunk * JJ * 2;
  const size_t z_bytes = (size_t)NN * NN * 4;  // Z aliases wt; ensure region holds both
  u16* wt = (u16*)alloc(wt_bytes > z_bytes ? wt_bytes : z_bytes);
  float* Z = (float*)wt;

  k_ln<<<NN, 128, 0, stream>>>(emb, gam, bet, e, ehi, elo);
  k_zg<<<dim3(16, 16), 256, 0, stream>>>(ehi, elo, Z);
  k_sm<<<NN, 256, 0, stream>>>(Z, Abf);
  k_tc<<<dim3(NN / 64, CC / 64, BB), 256, 0, stream>>>(x, xt, xbf);
  k_wpt<<<dim3(2, 2, KI), 256, 0, stream>>>(wp, wpt);
  k_bias<<<NN, 128, 0, stream>>>(e, bp, bias);

  // y1 = A @ x   (emits y1t = transposed copy for G2's A operand)
  gemm_bf16<0><<<dim3(16, 32), 256, 0, stream>>>(Abf, NN, xt, NN, 32, y1t, y1, nullptr);
  // y2 = 2 A @ y1 - x
  gemm_bf16<1><<<dim3(16, 32), 256, 0, stream>>>(y1t, NN, Abf, NN, 32, y2, nullptr, xbf);

  for (int nb = 0; nb < NN; nb += chunk) {
    gemm_bf16<2><<<dim3(JJ / 128, chunk / 128), 256, 0, stream>>>(
        wpt, DD, ehi + (size_t)nb * DD, DD, 2, wt, nullptr, nullptr);
    stage_b<<<chunk, 256, 0, stream>>>(xbf, y1, y2, wt, bias, out, nb);
  }
}

// Round 10
// 355.148 us; speedup vs baseline: 1.5796x; 1.5796x over previous
//
#include <hip/hip_runtime.h>

#define DI __device__ __forceinline__

typedef unsigned short u16;
typedef short short8 __attribute__((ext_vector_type(8)));
typedef float f32x4 __attribute__((ext_vector_type(4)));
typedef u16 u16x4 __attribute__((ext_vector_type(4)));

#define NN 2048
#define CC 128
#define BB 32
#define DD 128
#define OO 128
#define KI 384
#define JJ 49152  // 128*384

DI u16 f2bf(float f) {
  union { float f; unsigned u; } v; v.f = f;
  return (u16)((v.u + 0x7fffu + ((v.u >> 16) & 1u)) >> 16);  // RNE
}
DI float bf2f(u16 h) {
  union { unsigned u; float f; } v; v.u = ((unsigned)h) << 16;
  return v.f;
}

typedef __attribute__((address_space(3))) unsigned int lds_u32;
typedef __attribute__((address_space(1))) unsigned int glob_u32;

DI void gl16(const void* g, void* l) {
  __builtin_amdgcn_global_load_lds((const glob_u32*)g, (lds_u32*)l, 16, 0, 0);
}

// ---------------- LayerNorm: e = LN(emb)*gamma + beta; emit fp32 + bf16 hi/lo ----------------
__global__ __launch_bounds__(128)
void k_ln(const float* __restrict__ emb, const float* __restrict__ gam,
          const float* __restrict__ bet, float* __restrict__ e,
          u16* __restrict__ ehi, u16* __restrict__ elo) {
  __shared__ float s2[2], q2[2];
  const int n = blockIdx.x, t = threadIdx.x;
  const float v = emb[(size_t)n * DD + t];
  float s = v;
  #pragma unroll
  for (int off = 32; off; off >>= 1) s += __shfl_down(s, off);
  if ((t & 63) == 0) s2[t >> 6] = s;
  __syncthreads();
  const float mu = (s2[0] + s2[1]) * (1.f / 128.f);
  const float dv = v - mu;
  float q = dv * dv;
  #pragma unroll
  for (int off = 32; off; off >>= 1) q += __shfl_down(q, off);
  if ((t & 63) == 0) q2[t >> 6] = q;
  __syncthreads();
  const float var = (q2[0] + q2[1]) * (1.f / 128.f);
  const float ev = dv * rsqrtf(var + 1e-12f) * gam[t] + bet[t];
  e[(size_t)n * DD + t] = ev;
  const u16 hi = f2bf(ev);
  ehi[(size_t)n * DD + t] = hi;
  elo[(size_t)n * DD + t] = f2bf(ev - bf2f(hi));
}

// ---------------- Z = elu(e e^T) via split-bf16 MFMA (hi*hi + hi*lo + lo*hi) ----------------
__global__ __launch_bounds__(256, 2)
void k_zg(const u16* __restrict__ ehi, const u16* __restrict__ elo, float* __restrict__ Z) {
  __shared__ char smem[32768];
  const int t = threadIdx.x;
  const int w = t >> 6, l = t & 63;
  const int l15 = l & 15, kg = l >> 4;
  const int wr = (w >> 1) * 64, wc = (w & 1) * 64;
  const int row0 = blockIdx.x * 128, col0 = blockIdx.y * 128;

  f32x4 acc[4][4];
  #pragma unroll
  for (int i = 0; i < 4; ++i)
    #pragma unroll
    for (int j = 0; j < 4; ++j) { f32x4 z = {0.f, 0.f, 0.f, 0.f}; acc[i][j] = z; }

  const int ra = t >> 3, sa = t & 7;
  #pragma unroll 1
  for (int it = 0; it < 6; ++it) {
    const int term = it >> 1;
    const int k0 = (it & 1) * 64;
    const u16* As = (term == 2) ? elo : ehi;
    const u16* Bs = (term == 1) ? elo : ehi;
    __syncthreads();
    #pragma unroll
    for (int i = 0; i < 4; ++i) {
      const int r = i * 32 + ra;
      const int ss = sa ^ (r & 7);
      gl16(As + (size_t)(row0 + r) * DD + k0 + ss * 8, smem + i * 4096 + t * 16);
      gl16(Bs + (size_t)(col0 + r) * DD + k0 + ss * 8, smem + 16384 + i * 4096 + t * 16);
    }
    __syncthreads();
    short8 af[2][4], bfv[2][4];
    #pragma unroll
    for (int mt = 0; mt < 4; ++mt) {
      const int row = wr + mt * 16 + l15;
      #pragma unroll
      for (int ks = 0; ks < 2; ++ks) {
        const int sl = (ks * 4 + kg) ^ (row & 7);
        af[ks][mt] = *(const short8*)(smem + row * 128 + sl * 16);
      }
    }
    #pragma unroll
    for (int nt = 0; nt < 4; ++nt) {
      const int row = wc + nt * 16 + l15;
      #pragma unroll
      for (int ks = 0; ks < 2; ++ks) {
        const int sl = (ks * 4 + kg) ^ (row & 7);
        bfv[ks][nt] = *(const short8*)(smem + 16384 + row * 128 + sl * 16);
      }
    }
    #pragma unroll
    for (int ks = 0; ks < 2; ++ks)
      #pragma unroll
      for (int mt = 0; mt < 4; ++mt)
        #pragma unroll
        for (int nt = 0; nt < 4; ++nt)
          acc[mt][nt] = __builtin_amdgcn_mfma_f32_16x16x32_bf16(af[ks][mt], bfv[ks][nt], acc[mt][nt], 0, 0, 0);
  }
  #pragma unroll
  for (int mt = 0; mt < 4; ++mt) {
    const int n_ = row0 + wr + mt * 16 + kg * 4;
    #pragma unroll
    for (int nt = 0; nt < 4; ++nt) {
      const int m_ = col0 + wc + nt * 16 + l15;
      #pragma unroll
      for (int r = 0; r < 4; ++r) {
        const float v = acc[mt][nt][r];
        Z[(size_t)(n_ + r) * NN + m_] = (v > 0.f) ? v : expm1f(v);
      }
    }
  }
}

// ---------------- row softmax over Z -> A_bf16 ----------------
__global__ __launch_bounds__(256)
void k_sm(const float* __restrict__ Z, u16* __restrict__ Abf) {
  __shared__ float red[4];
  const int n = blockIdx.x, t = threadIdx.x, w = t >> 6;
  const float* zr = Z + (size_t)n * NN + t * 8;
  float4 v0 = *(const float4*)(zr);
  float4 v1 = *(const float4*)(zr + 4);
  float z[8] = {v0.x, v0.y, v0.z, v0.w, v1.x, v1.y, v1.z, v1.w};
  float mx = z[0];
  #pragma unroll
  for (int i = 1; i < 8; ++i) mx = fmaxf(mx, z[i]);
  #pragma unroll
  for (int off = 32; off; off >>= 1) mx = fmaxf(mx, __shfl_xor(mx, off));
  if ((t & 63) == 0) red[w] = mx;
  __syncthreads();
  mx = fmaxf(fmaxf(red[0], red[1]), fmaxf(red[2], red[3]));
  __syncthreads();
  float sm = 0.f;
  #pragma unroll
  for (int i = 0; i < 8; ++i) { z[i] = expf(z[i] - mx); sm += z[i]; }
  #pragma unroll
  for (int off = 32; off; off >>= 1) sm += __shfl_xor(sm, off);
  if ((t & 63) == 0) red[w] = sm;
  __syncthreads();
  const float inv = 1.f / (red[0] + red[1] + red[2] + red[3]);
  short8 pk;
  #pragma unroll
  for (int i = 0; i < 8; ++i) pk[i] = (short)f2bf(z[i] * inv);
  *(short8*)(Abf + (size_t)n * NN + t * 8) = pk;
}

// ---------------- transpose-cast x[b][m][c] -> xt[b][c][m] + xbf[b][m][c] (bf16) ----------------
__global__ __launch_bounds__(256)
void k_tc(const float* __restrict__ x, u16* __restrict__ xt, u16* __restrict__ xbf) {
  __shared__ float ld[64 * 68];
  const int t = threadIdx.x;
  const int m0 = blockIdx.x * 64, c0 = blockIdx.y * 64, b = blockIdx.z;
  const float* xb = x + (size_t)b * NN * CC;
  u16* xfb = xbf + (size_t)b * NN * CC;
  #pragma unroll
  for (int i = 0; i < 4; ++i) {
    const int m = i * 16 + (t >> 4), c4 = (t & 15) * 4;
    const float4 v = *(const float4*)&xb[(size_t)(m0 + m) * CC + c0 + c4];
    *(float4*)&ld[m * 68 + c4] = v;
    u16x4 cv = { f2bf(v.x), f2bf(v.y), f2bf(v.z), f2bf(v.w) };
    *(u16x4*)&xfb[(size_t)(m0 + m) * CC + c0 + c4] = cv;
  }
  __syncthreads();
  u16* xtb = xt + (size_t)b * CC * NN;
  #pragma unroll
  for (int i = 0; i < 4; ++i) {
    const int c = i * 16 + (t >> 4), m4 = (t & 15) * 4;
    u16x4 v = { f2bf(ld[(m4 + 0) * 68 + c]), f2bf(ld[(m4 + 1) * 68 + c]),
                f2bf(ld[(m4 + 2) * 68 + c]), f2bf(ld[(m4 + 3) * 68 + c]) };
    *(u16x4*)&xtb[(size_t)(c0 + c) * NN + m0 + m4] = v;
  }
}

// ---------------- transpose-cast Wp[d][ki][o] -> Wp_t[(o*384+ki)][d] (bf16) ----------------
__global__ __launch_bounds__(256)
void k_wpt(const float* __restrict__ wp, u16* __restrict__ wpt) {
  __shared__ float ld[64 * 68];
  const int t = threadIdx.x;
  const int d0 = blockIdx.x * 64, o0 = blockIdx.y * 64, ki = blockIdx.z;
  #pragma unroll
  for (int i = 0; i < 4; ++i) {
    const int d = i * 16 + (t >> 4), o4 = (t & 15) * 4;
    *(float4*)&ld[d * 68 + o4] = *(const float4*)&wp[((size_t)(d0 + d) * KI + ki) * OO + o0 + o4];
  }
  __syncthreads();
  #pragma unroll
  for (int i = 0; i < 4; ++i) {
    const int o = i * 16 + (t >> 4), d4 = (t & 15) * 4;
    u16x4 v = { f2bf(ld[(d4 + 0) * 68 + o]), f2bf(ld[(d4 + 1) * 68 + o]),
                f2bf(ld[(d4 + 2) * 68 + o]), f2bf(ld[(d4 + 3) * 68 + o]) };
    *(u16x4*)&wpt[((size_t)(o0 + o) * KI + ki) * DD + d0 + d4] = v;
  }
}

// ---------------- bias[n][o] = e[n]·bias_pool[:,o] (fp32) ----------------
__global__ __launch_bounds__(128)
void k_bias(const float* __restrict__ e, const float* __restrict__ bp, float* __restrict__ bias) {
  const int n = blockIdx.x, o = threadIdx.x;
  const float* er = e + (size_t)n * DD;
  float acc = 0.f;
  for (int d = 0; d < 128; ++d) acc = fmaf(er[d], bp[(size_t)d * OO + o], acc);
  bias[(size_t)n * OO + o] = acc;
}

// ---------------- shared 128x128-tile bf16 MFMA GEMM (m97-style, BK=64) ----------------
// MODE 0: D[n][c] = sum_m A[n][m]*xt[b][c][m]; store y1t[b][c][n] + y1[b][n][c] (LDS bounce).
// MODE 1: D[c][n] = sum_m y1t[b][c][m]*A[n][m]; store y2[b][n][c] = 2*D - x (x as bf16).
// MODE 2: D[j][nl] = sum_d Wp_t[j][d]*ehi[n][d]; store to tile-major wt2[jt][node][128]:
//         each block writes one dense 32KB region (kept from r8 — FETCH 19.6->7.2MB win).
//         NO nontemporal stores anywhere: r9 showed nt on gfx950 bypasses L2 write-
//         combining -> partial-line RMW, WRITE_SIZE 100->170MB, 1.5x slower.
template<int MODE>
__global__ __launch_bounds__(256, 2)
void gemm_bf16(const u16* __restrict__ Ab, int lda,
               const u16* __restrict__ Bb, int ldb, int ksteps,
               u16* __restrict__ out0, u16* __restrict__ out1,
               const u16* __restrict__ xaux) {
  __shared__ char smem[34816];  // 32KB staging; 34.8KB bounce (MODE 0)
  const int t = threadIdx.x;
  const int w = t >> 6, l = t & 63;
  const int l15 = l & 15, kg = l >> 4;
  const int wr = (w >> 1) * 64, wc = (w & 1) * 64;

  const u16 *Abase, *Bbase;
  int row0 = 0, col0 = 0, b = 0;
  if constexpr (MODE == 0 || MODE == 1) {
    // grid is dim3(16,32) = 512 blocks; hw-linear id round-robins XCDs (%8)
    const int lin = blockIdx.x + (int)gridDim.x * blockIdx.y;
    const int xcd = lin & 7, pos = lin >> 3;
    const int tile = xcd * 2 + (pos & 1);  // 0..15 n-tile
    b = pos >> 1;                           // 0..31 batch
    if constexpr (MODE == 0) {
      row0 = tile * 128;
      Abase = Ab + (size_t)row0 * lda;
      Bbase = Bb + (size_t)b * CC * NN;
    } else {
      col0 = tile * 128;
      Abase = Ab + (size_t)b * CC * NN;
      Bbase = Bb + (size_t)col0 * NN;
    }
  } else {
    row0 = blockIdx.x * 128; col0 = blockIdx.y * 128;
    Abase = Ab + (size_t)row0 * 128;
    Bbase = Bb + (size_t)col0 * 128;
  }

  f32x4 acc[4][4];
  #pragma unroll
  for (int i = 0; i < 4; ++i)
    #pragma unroll
    for (int j = 0; j < 4; ++j) { f32x4 z = {0.f, 0.f, 0.f, 0.f}; acc[i][j] = z; }

  const int ra = t >> 3, sa = t & 7;
  for (int kt = 0; kt < ksteps; ++kt) {
    const int k0 = kt * 64;
    __syncthreads();
    #pragma unroll
    for (int i = 0; i < 4; ++i) {
      const int r = i * 32 + ra;
      const int ss = sa ^ (r & 7);
      gl16(Abase + (size_t)r * lda + k0 + ss * 8, smem + i * 4096 + t * 16);
    }
    #pragma unroll
    for (int i = 0; i < 4; ++i) {
      const int r = i * 32 + ra;
      const int ss = sa ^ (r & 7);
      gl16(Bbase + (size_t)r * ldb + k0 + ss * 8, smem + 16384 + i * 4096 + t * 16);
    }
    __syncthreads();
    short8 af[2][4], bfv[2][4];
    #pragma unroll
    for (int mt = 0; mt < 4; ++mt) {
      const int row = wr + mt * 16 + l15;
      #pragma unroll
      for (int ks = 0; ks < 2; ++ks) {
        const int sl = (ks * 4 + kg) ^ (row & 7);
        af[ks][mt] = *(const short8*)(smem + row * 128 + sl * 16);
      }
    }
    #pragma unroll
    for (int nt = 0; nt < 4; ++nt) {
      const int row = wc + nt * 16 + l15;
      #pragma unroll
      for (int ks = 0; ks < 2; ++ks) {
        const int sl = (ks * 4 + kg) ^ (row & 7);
        bfv[ks][nt] = *(const short8*)(smem + 16384 + row * 128 + sl * 16);
      }
    }
    #pragma unroll
    for (int ks = 0; ks < 2; ++ks)
      #pragma unroll
      for (int mt = 0; mt < 4; ++mt)
        #pragma unroll
        for (int nt = 0; nt < 4; ++nt)
          acc[mt][nt] = __builtin_amdgcn_mfma_f32_16x16x32_bf16(af[ks][mt], bfv[ks][nt], acc[mt][nt], 0, 0, 0);
  }

  if constexpr (MODE == 0) {
    u16* y1t = out0 + (size_t)b * CC * NN;
    #pragma unroll
    for (int mt = 0; mt < 4; ++mt) {
      const int n_ = row0 + wr + mt * 16 + kg * 4;
      #pragma unroll
      for (int nt = 0; nt < 4; ++nt) {
        const int c_ = wc + nt * 16 + l15;
        u16x4 v = { f2bf(acc[mt][nt][0]), f2bf(acc[mt][nt][1]),
                    f2bf(acc[mt][nt][2]), f2bf(acc[mt][nt][3]) };
        *(u16x4*)(y1t + (size_t)c_ * NN + n_) = v;
      }
    }
    __syncthreads();
    u16* L = (u16*)smem;  // [128 n][136 c]
    #pragma unroll
    for (int mt = 0; mt < 4; ++mt) {
      const int nl = wr + mt * 16 + kg * 4;
      #pragma unroll
      for (int nt = 0; nt < 4; ++nt) {
        const int c_ = wc + nt * 16 + l15;
        #pragma unroll
        for (int r = 0; r < 4; ++r) L[(nl + r) * 136 + c_] = f2bf(acc[mt][nt][r]);
      }
    }
    __syncthreads();
    u16* y1o = out1 + (size_t)b * NN * CC;
    const int nl2 = t >> 1, ch = (t & 1) * 64;
    #pragma unroll
    for (int q = 0; q < 8; ++q) {
      short8 vv = *(const short8*)(L + nl2 * 136 + ch + q * 8);
      *(short8*)(y1o + (size_t)(row0 + nl2) * CC + ch + q * 8) = vv;
    }
  } else if constexpr (MODE == 1) {
    const u16* xb = xaux + (size_t)b * NN * CC;
    u16* y2b = out0 + (size_t)b * NN * CC;
    #pragma unroll
    for (int mt = 0; mt < 4; ++mt) {
      const int c_ = wr + mt * 16 + kg * 4;
      #pragma unroll
      for (int nt = 0; nt < 4; ++nt) {
        const int n_ = col0 + wc + nt * 16 + l15;
        const u16x4 xv = *(const u16x4*)(xb + (size_t)n_ * CC + c_);
        u16x4 v = { f2bf(2.f * acc[mt][nt][0] - bf2f(xv[0])),
                    f2bf(2.f * acc[mt][nt][1] - bf2f(xv[1])),
                    f2bf(2.f * acc[mt][nt][2] - bf2f(xv[2])),
                    f2bf(2.f * acc[mt][nt][3] - bf2f(xv[3])) };
        *(u16x4*)(y2b + (size_t)n_ * CC + c_) = v;
      }
    }
  } else {
    // tile-major W: plane jt = row0/128, within-plane [node][128 jsub], dense 32KB/block
    u16* wtb = out0 + (size_t)(row0 >> 7) * ((size_t)gridDim.y << 14);
    #pragma unroll
    for (int mt = 0; mt < 4; ++mt) {
      const int jl = wr + mt * 16 + kg * 4;
      #pragma unroll
      for (int nt = 0; nt < 4; ++nt) {
        const int nl = col0 + wc + nt * 16 + l15;
        u16x4 v = { f2bf(acc[mt][nt][0]), f2bf(acc[mt][nt][1]),
                    f2bf(acc[mt][nt][2]), f2bf(acc[mt][nt][3]) };
        *(u16x4*)(wtb + (size_t)nl * 128 + jl) = v;
      }
    }
  }
}

// ---------------- per-node GEMM: out[b][n][o] = X~[32,384]@W~[384,128] + bias ----------------
// W read from tile-major wt2[jt][node][128]: element (o,ki) -> plane 3*o + ki/128,
// jsub = ki%128 (KI = 384 = 3*128, verified bijection).
__global__ __launch_bounds__(256, 4)
void stage_b(const u16* __restrict__ xbf, const u16* __restrict__ y1,
             const u16* __restrict__ y2, const u16* __restrict__ Wt,
             const float* __restrict__ bias, float* __restrict__ out, int nbase) {
  const int t = threadIdx.x, w = t >> 6, l = t & 63;
  const int l15 = l & 15, kg = l >> 4;
  const int n = nbase + blockIdx.x;
  const size_t pstride = (size_t)gridDim.x << 7;  // chunk*128 elements per plane
  const u16* Wn = Wt + (size_t)blockIdx.x * 128;  // node's 256B row within each plane
  f32x4 acc[2][2];
  {
    f32x4 z = {0.f, 0.f, 0.f, 0.f};
    acc[0][0] = z; acc[0][1] = z; acc[1][0] = z; acc[1][1] = z;
  }
  #pragma unroll
  for (int ch2 = 0; ch2 < 3; ++ch2) {
    const u16* src = (ch2 == 0) ? xbf : (ch2 == 1) ? y1 : y2;
    #pragma unroll
    for (int ks = 0; ks < 4; ++ks) {
      short8 af[2];
      #pragma unroll
      for (int mt = 0; mt < 2; ++mt) {
        const int bb2 = mt * 16 + l15;
        af[mt] = *(const short8*)(src + ((size_t)bb2 * NN + n) * CC + ks * 32 + kg * 8);
      }
      #pragma unroll
      for (int ot = 0; ot < 2; ++ot) {
        const int o = w * 32 + ot * 16 + l15;
        short8 bv = *(const short8*)(Wn + (size_t)(3 * o + ch2) * pstride + ks * 32 + kg * 8);
        acc[0][ot] = __builtin_amdgcn_mfma_f32_16x16x32_bf16(af[0], bv, acc[0][ot], 0, 0, 0);
        acc[1][ot] = __builtin_amdgcn_mfma_f32_16x16x32_bf16(af[1], bv, acc[1][ot], 0, 0, 0);
      }
    }
  }
  #pragma unroll
  for (int ot = 0; ot < 2; ++ot) {
    const int o = w * 32 + ot * 16 + l15;
    const float bs = bias[(size_t)n * OO + o];
    #pragma unroll
    for (int mt = 0; mt < 2; ++mt)
      #pragma unroll
      for (int r = 0; r < 4; ++r) {
        const int bb2 = mt * 16 + kg * 4 + r;
        out[((size_t)bb2 * NN + n) * OO + o] = acc[mt][ot][r] + bs;
      }
  }
}

extern "C" void kernel_launch(void* const* d_in, const int* in_sizes, int n_in,
                              void* d_out, int out_size, void* d_ws, size_t ws_size,
                              hipStream_t stream) {
  (void)in_sizes; (void)n_in; (void)out_size;
  const float* x   = (const float*)d_in[0];
  const float* emb = (const float*)d_in[1];
  const float* wp  = (const float*)d_in[2];
  const float* bp  = (const float*)d_in[3];
  const float* gam = (const float*)d_in[4];
  const float* bet = (const float*)d_in[5];
  float* out = (float*)d_out;
  char* ws = (char*)d_ws;

  size_t off = 0;
  auto alloc = [&](size_t bytes) -> void* {
    void* p = (void*)(ws + off);
    off += (bytes + 511) & ~(size_t)511;
    return p;
  };
  float* e    = (float*)alloc((size_t)NN * DD * 4);
  u16*   ehi  = (u16*)  alloc((size_t)NN * DD * 2);
  u16*   elo  = (u16*)  alloc((size_t)NN * DD * 2);
  float* bias = (float*)alloc((size_t)NN * OO * 4);
  u16*   Abf  = (u16*)  alloc((size_t)NN * NN * 2);
  u16*   xt   = (u16*)  alloc((size_t)BB * CC * NN * 2);
  u16*   xbf  = (u16*)  alloc((size_t)BB * NN * CC * 2);
  u16*   y1t  = (u16*)  alloc((size_t)BB * CC * NN * 2);
  u16*   y1   = (u16*)  alloc((size_t)BB * NN * CC * 2);
  u16*   y2   = (u16*)  alloc((size_t)BB * NN * CC * 2);
  u16*   wpt  = (u16*)  alloc((size_t)JJ * DD * 2);
  const size_t rem = (ws_size > off) ? (ws_size - off) : 0;
  int chunk = 1024;  // 96MB W-chunk
  while (chunk > 128 && (size_t)chunk * JJ * 2 > rem) chunk >>= 1;
  size_t wt_bytes = (size_t)chunk * JJ * 2;
  const size_t z_bytes = (size_t)NN * NN * 4;  // Z aliases wt; ensure region holds both
  u16* wt = (u16*)alloc(wt_bytes > z_bytes ? wt_bytes : z_bytes);
  float* Z = (float*)wt;

  k_ln<<<NN, 128, 0, stream>>>(emb, gam, bet, e, ehi, elo);
  k_zg<<<dim3(16, 16), 256, 0, stream>>>(ehi, elo, Z);
  k_sm<<<NN, 256, 0, stream>>>(Z, Abf);
  k_tc<<<dim3(NN / 64, CC / 64, BB), 256, 0, stream>>>(x, xt, xbf);
  k_wpt<<<dim3(2, 2, KI), 256, 0, stream>>>(wp, wpt);
  k_bias<<<NN, 128, 0, stream>>>(e, bp, bias);

  // y1 = A @ x   (emits y1t = transposed copy for G2's A operand)
  gemm_bf16<0><<<dim3(16, 32), 256, 0, stream>>>(Abf, NN, xt, NN, 32, y1t, y1, nullptr);
  // y2 = 2 A @ y1 - x
  gemm_bf16<1><<<dim3(16, 32), 256, 0, stream>>>(y1t, NN, Abf, NN, 32, y2, nullptr, xbf);

  for (int nb = 0; nb < NN; nb += chunk) {
    gemm_bf16<2><<<dim3(JJ / 128, chunk / 128), 256, 0, stream>>>(
        wpt, DD, ehi + (size_t)nb * DD, DD, 2, wt, nullptr, nullptr);
    stage_b<<<chunk, 256, 0, stream>>>(xbf, y1, y2, wt, bias, out, nb);
  }
}